// Round 1
// baseline (81.727 us; speedup 1.0000x reference)
//
#include <hip/hip_runtime.h>

#define BB 16
#define HH 512
#define WW 512
// C = 3 floats per pixel

__global__ __launch_bounds__(256) void warp2_kernel(
    const float* __restrict__ frame0,
    const float* __restrict__ frame1,
    const float* __restrict__ f01,
    const float* __restrict__ f10,
    float* __restrict__ out)
{
    const int Npix = BB * HH * WW;          // 4,194,304
    const int total = 2 * Npix;
    const int stride = gridDim.x * blockDim.x;

    for (int idx = blockIdx.x * blockDim.x + threadIdx.x; idx < total; idx += stride) {
        const int which = idx >= Npix;               // 0: out0 = warp(frame0, f10); 1: out1 = warp(frame1, f01)
        const int p = idx - which * Npix;
        const float* __restrict__ img  = which ? frame1 : frame0;
        const float* __restrict__ flow = which ? f01    : f10;

        const int b   = p >> 18;          // / (512*512)
        const int rem = p & 262143;
        const int y   = rem >> 9;         // / 512
        const int x   = rem & 511;

        const float2 fl = *reinterpret_cast<const float2*>(flow + 2 * (size_t)p);
        const float qy = (float)y - fl.x;   // flow[...,0] is dy
        const float qx = (float)x - fl.y;   // flow[...,1] is dx

        float y0f = fminf(fmaxf(floorf(qy), 0.0f), (float)(HH - 2));
        float x0f = fminf(fmaxf(floorf(qx), 0.0f), (float)(WW - 2));
        const float ay = fminf(fmaxf(qy - y0f, 0.0f), 1.0f);
        const float ax = fminf(fmaxf(qx - x0f, 0.0f), 1.0f);
        const int y0 = (int)y0f;
        const int x0 = (int)x0f;

        const float* rowt = img + ((size_t)((b * HH + y0) * WW + x0)) * 3;
        const float* rowb = rowt + WW * 3;

        const float3 tl = *reinterpret_cast<const float3*>(rowt);
        const float3 tr = *reinterpret_cast<const float3*>(rowt + 3);
        const float3 bl = *reinterpret_cast<const float3*>(rowb);
        const float3 br = *reinterpret_cast<const float3*>(rowb + 3);

        // top = tl + ax*(tr-tl); bot = bl + ax*(br-bl); out = top + ay*(bot-top)
        const float t0 = fmaf(ax, tr.x - tl.x, tl.x);
        const float t1 = fmaf(ax, tr.y - tl.y, tl.y);
        const float t2 = fmaf(ax, tr.z - tl.z, tl.z);
        const float b0 = fmaf(ax, br.x - bl.x, bl.x);
        const float b1 = fmaf(ax, br.y - bl.y, bl.y);
        const float b2 = fmaf(ax, br.z - bl.z, bl.z);

        float* o = out + 3 * (size_t)idx;   // concatenated layout: offset 3*idx works for both halves
        o[0] = fmaf(ay, b0 - t0, t0);
        o[1] = fmaf(ay, b1 - t1, t1);
        o[2] = fmaf(ay, b2 - t2, t2);
    }
}

extern "C" void kernel_launch(void* const* d_in, const int* in_sizes, int n_in,
                              void* d_out, int out_size, void* d_ws, size_t ws_size,
                              hipStream_t stream) {
    const float* frame0 = (const float*)d_in[0];
    const float* frame1 = (const float*)d_in[1];
    const float* f01    = (const float*)d_in[2];
    const float* f10    = (const float*)d_in[3];
    float* out = (float*)d_out;

    const int blocks = 4096;
    warp2_kernel<<<blocks, 256, 0, stream>>>(frame0, frame1, f01, f10, out);
}